// Round 9
// baseline (455.738 us; speedup 1.0000x reference)
//
#include <hip/hip_runtime.h>
#include <hip/hip_bf16.h>
#include <math.h>

#define BATCH 16384

typedef unsigned short u16;
typedef short bf16x8 __attribute__((ext_vector_type(8)));
typedef float f32x4 __attribute__((ext_vector_type(4)));
typedef u16 u16x8 __attribute__((ext_vector_type(8)));
typedef u16 u16x2 __attribute__((ext_vector_type(2)));

__constant__ int PERMS_C[6][3] = {{0,1,2},{0,2,1},{1,0,2},{1,2,0},{2,0,1},{2,1,0}};

__device__ inline float bf2f(u16 u) {
    unsigned int x = ((unsigned int)u) << 16;
    float f; __builtin_memcpy(&f, &x, 4); return f;
}
__device__ inline u16 f2bf(float f) {
    __hip_bfloat16 h = __float2bfloat16(f);
    u16 u; __builtin_memcpy(&u, &h, 2); return u;
}
// tanh-approx gelu: x * sigmoid(1.5957691x + 0.0713548x^3). |err| ~3e-4,
// below the bf16 rounding already applied to H1/H2 values.
__device__ __forceinline__ float gelu_fast(float x) {
    float t = x * (1.59576912f + x * x * 0.07135481f);
    return x / (1.0f + __expf(-t));
}

// async global->LDS, 16B per lane, wave-uniform LDS base + lane*16
__device__ inline void gload_lds16(const u16* g, u16* l) {
    __builtin_amdgcn_global_load_lds(
        (const __attribute__((address_space(1))) unsigned int*)g,
        (__attribute__((address_space(3))) unsigned int*)l,
        16, 0, 0);
}

// ---------------------------------------------------------------------------
// prep: convert seq_embed to bf16, build transposed bf16 weight blocks,
// concatenated biases.
// ---------------------------------------------------------------------------
__global__ __launch_bounds__(256) void prep_kernel(
    const float* __restrict__ seq,
    const float* __restrict__ pw1, const float* __restrict__ pw2,
    const float* __restrict__ fw1, const float* __restrict__ fw2,
    const float* __restrict__ pb1, const float* __restrict__ pb2,
    const float* __restrict__ fb1, const float* __restrict__ fb2,
    u16* __restrict__ sb, u16* __restrict__ W1T, u16* __restrict__ W2T,
    float* __restrict__ bias1, float* __restrict__ bias2)
{
    const int N0 = BATCH * 512;      // seq conversion
    const int N1 = 1024 * 512;       // W1T
    const int N2 = 768 * 512;        // W2T
    const int N3 = 1024;             // bias1
    const int N4 = 768;              // bias2
    int i = blockIdx.x * 256 + threadIdx.x;
    if (i < N0) { sb[i] = f2bf(seq[i]); return; }
    i -= N0;
    if (i < N1) {
        int n = i >> 9, k = i & 511;
        float v = (n < 512) ? pw1[(size_t)k * 512 + n] : fw1[(size_t)k * 512 + (n - 512)];
        W1T[i] = f2bf(v); return;
    }
    i -= N1;
    if (i < N2) {
        int n = i >> 9, k = i & 511;
        float v = (n < 256) ? pw2[(size_t)k * 256 + n] : fw2[(size_t)k * 512 + (n - 256)];
        W2T[i] = f2bf(v); return;
    }
    i -= N2;
    if (i < N3) { bias1[i] = (i < 512) ? pb1[i] : fb1[i - 512]; return; }
    i -= N3;
    if (i < N4) { bias2[i] = (i < 256) ? pb2[i] : fb2[i - 256]; return; }
}

// ---------------------------------------------------------------------------
// bf16 MFMA GEMM: C[M,N](bf16) = A[M,K] @ Bt[N,K]^T + bias.
// 128x128 tile, 4 waves, BK=64, global_load_lds staging, linear LDS.
// Used only for Z = seq @ [pw1|fw1] + bias1.
// ---------------------------------------------------------------------------
__global__ __launch_bounds__(256) void gemm_bf16(
    const u16* __restrict__ A, int lda,
    const u16* __restrict__ Bt, const float* __restrict__ bias,
    u16* __restrict__ C, int M, int N, int K)
{
    __shared__ __align__(16) u16 As[128 * 64];
    __shared__ __align__(16) u16 Bs[128 * 64];

    const int bm = blockIdx.x * 128;
    const int bn = blockIdx.y * 128;

    const int tid = threadIdx.x;
    const int wv = tid >> 6;
    const int lane = tid & 63;
    const int wr = wv >> 1;
    const int wc = wv & 1;

    const int lrow = lane >> 3;
    const int lcol = (lane & 7) << 3;

    f32x4 acc[4][4];
#pragma unroll
    for (int i = 0; i < 4; ++i)
#pragma unroll
        for (int j = 0; j < 4; ++j) acc[i][j] = (f32x4){0.f, 0.f, 0.f, 0.f};

    for (int k0 = 0; k0 < K; k0 += 64) {
#pragma unroll
        for (int q = 0; q < 4; ++q) {
            const int c = wv * 4 + q;
            const int row = c * 8 + lrow;
            gload_lds16(&A[(size_t)(bm + row) * lda + k0 + lcol], &As[c * 512]);
            gload_lds16(&Bt[(size_t)(bn + row) * K + k0 + lcol], &Bs[c * 512]);
        }
        __syncthreads();

#pragma unroll
        for (int ks = 0; ks < 64; ks += 32) {
            int kk = ks + (lane >> 4) * 8;
            bf16x8 af[4], bfr[4];
#pragma unroll
            for (int i = 0; i < 4; ++i)
                af[i] = *reinterpret_cast<const bf16x8*>(&As[(wr * 64 + i * 16 + (lane & 15)) * 64 + kk]);
#pragma unroll
            for (int j = 0; j < 4; ++j)
                bfr[j] = *reinterpret_cast<const bf16x8*>(&Bs[(wc * 64 + j * 16 + (lane & 15)) * 64 + kk]);
#pragma unroll
            for (int i = 0; i < 4; ++i)
#pragma unroll
                for (int j = 0; j < 4; ++j)
                    acc[i][j] = __builtin_amdgcn_mfma_f32_16x16x32_bf16(af[i], bfr[j], acc[i][j], 0, 0, 0);
        }
        __syncthreads();
    }

    const int r4 = (lane >> 4) * 4;
    const int cn = lane & 15;
#pragma unroll
    for (int i = 0; i < 4; ++i) {
#pragma unroll
        for (int j = 0; j < 4; ++j) {
            int gcol = bn + wc * 64 + j * 16 + cn;
            float bsv = bias[gcol];
#pragma unroll
            for (int r = 0; r < 4; ++r) {
                int grow = bm + wr * 64 + i * 16 + r4 + r;
                C[(size_t)grow * N + gcol] = f2bf(acc[i][j][r] + bsv);
            }
        }
    }
}

// ---------------------------------------------------------------------------
// decode3 v3: fused 3-step decode. 32 rows/block, 512 threads (8 waves),
// 512 blocks -> 2 blocks/CU (phase overlap across blocks). Z held in
// REGISTERS (amdgpu_waves_per_eu(4,4) grants the 128-VGPR budget so the
// 32-reg zreg array is NOT spilled -- R7's failure mode).
// ---------------------------------------------------------------------------

template<int NS>
__device__ __forceinline__ void h1_phase(
    const float* __restrict__ wsrc, int cw0,
    const u16x2 (&zreg)[32], int gcol0, char* h1base,
    const float (*state)[20], const int* rid)
{
    float w[NS + 3][2];
#pragma unroll
    for (int r = 0; r < NS + 3; ++r) {
        float2 v = *reinterpret_cast<const float2*>(&wsrc[(size_t)r * 512 + cw0]);
        w[r][0] = v.x; w[r][1] = v.y;
    }
#pragma unroll
    for (int row = 0; row < 32; ++row) {
        const int ridx = rid[row];
        float s[NS];
        if constexpr (NS == 6) {
            float4 a = *reinterpret_cast<const float4*>(&state[row][0]);
            float2 b = *reinterpret_cast<const float2*>(&state[row][4]);
            s[0] = a.x; s[1] = a.y; s[2] = a.z; s[3] = a.w; s[4] = b.x; s[5] = b.y;
        } else {
            float4 a = *reinterpret_cast<const float4*>(&state[row][8]);
            float4 b = *reinterpret_cast<const float4*>(&state[row][12]);
            float4 c = *reinterpret_cast<const float4*>(&state[row][16]);
            s[0] = a.x; s[1] = a.y; s[2]  = a.z; s[3]  = a.w;
            s[4] = b.x; s[5] = b.y; s[6]  = b.z; s[7]  = b.w;
            s[8] = c.x; s[9] = c.y; s[10] = c.z; s[11] = c.w;
        }
        float d0 = (ridx == 0) ? w[NS][0] : ((ridx == 1) ? w[NS + 1][0] : w[NS + 2][0]);
        float d1 = (ridx == 0) ? w[NS][1] : ((ridx == 1) ? w[NS + 1][1] : w[NS + 2][1]);
#pragma unroll
        for (int j = 0; j < NS; ++j) { d0 += s[j] * w[j][0]; d1 += s[j] * w[j][1]; }
        float h0 = gelu_fast(bf2f(zreg[row][0]) + d0);
        float h1 = gelu_fast(bf2f(zreg[row][1]) + d1);
        unsigned int packed = (unsigned int)f2bf(h0) | ((unsigned int)f2bf(h1) << 16);
        int byte = (row * 2048 + gcol0 * 2) ^ ((row & 7) << 4);
        *reinterpret_cast<unsigned int*>(h1base + byte) = packed;
    }
}

__global__ void __attribute__((amdgpu_flat_work_group_size(512, 512)))
__attribute__((amdgpu_waves_per_eu(4, 4))) decode3(
    const u16* __restrict__ Z,
    const float* __restrict__ pw1s, const float* __restrict__ fw1s,
    const u16* __restrict__ W2T, const float* __restrict__ bias2,
    const float* __restrict__ pw3, const float* __restrict__ pb3,
    const float* __restrict__ fw3, const float* __restrict__ fb3,
    const float* __restrict__ freq, const float* __restrict__ presv,
    const float* __restrict__ enrich, const int* __restrict__ round_mask,
    const int* __restrict__ perm_idx,
    float* __restrict__ part, float* __restrict__ out)
{
    __shared__ __align__(16) u16 H1s[32 * 1024];   // 64 KB, XOR-swizzled
    __shared__ float redh[8][32][3];               // 3 KB
    __shared__ __align__(16) float state_s[32][20];// [0:6) pres, [8:20) full
    __shared__ int pidx_s[32];
    __shared__ int rid_s[32];

    const int tid = threadIdx.x;
    const int wv  = tid >> 6;   // 0..7
    const int l   = tid & 63;
    const int row0 = blockIdx.x * 32;

    // H1-phase thread geometry: thread = one column pair, all 32 rows.
    const int ci    = tid;            // column pair index (0..511)
    const int half  = ci >> 8;        // 0 = pres cols, 1 = full cols
    const int cw0   = (ci & 255) * 2; // col within half
    const int gcol0 = ci * 2;         // global H1 col
    char* h1base = reinterpret_cast<char*>(H1s);

    // ---- init ----
    {
        float* ss = &state_s[0][0];
        for (int i = tid; i < 32 * 20; i += 512) ss[i] = 0.f;
        if (tid < 32) {
            int pp = perm_idx[row0 + tid];
            pidx_s[tid] = pp;
            rid_s[tid] = PERMS_C[pp][0];
        }
    }

    // ---- Z -> registers (loaded once; reused across all 3 steps) ----
    u16x2 zreg[32];
#pragma unroll
    for (int r = 0; r < 32; ++r)
        zreg[r] = *reinterpret_cast<const u16x2*>(
            &Z[(size_t)(row0 + r) * 1024 + gcol0]);

    __syncthreads();

    // H2-phase wave geometry: wave wv covers cols [wv*96, wv*96+96)
    const int colbase = wv * 96;
    const bool needP = (colbase < 256);
    const bool needF = (colbase + 80) >= 256;

    float lf_acc = 0.f, bce_acc = 0.f, le_acc = 0.f, mm_acc = 0.f;

#pragma unroll 1
    for (int step = 0; step < 3; ++step) {
        // ---------------- H1 phase ----------------
        if (half == 0)
            h1_phase<6>(pw1s, cw0, zreg, gcol0, h1base, state_s, rid_s);
        else
            h1_phase<12>(fw1s, cw0, zreg, gcol0, h1base, state_s, rid_s);
        __syncthreads();

        // ---------------- H2 GEMM ----------------
        f32x4 acc[2][6];
#pragma unroll
        for (int rf = 0; rf < 2; ++rf)
#pragma unroll
            for (int cf = 0; cf < 6; ++cf) acc[rf][cf] = (f32x4){0.f, 0.f, 0.f, 0.f};

        const int ar = l & 15;
        const int ks = (l >> 4) * 8;
#pragma unroll 2
        for (int kf = 0; kf < 16; ++kf) {
            bf16x8 afP[2], afF[2];
            if (needP) {
#pragma unroll
                for (int rf = 0; rf < 2; ++rf) {
                    int row = rf * 16 + ar;
                    int byte = (row * 2048 + (kf * 32 + ks) * 2) ^ ((row & 7) << 4);
                    afP[rf] = *reinterpret_cast<const bf16x8*>(h1base + byte);
                }
            }
            if (needF) {
#pragma unroll
                for (int rf = 0; rf < 2; ++rf) {
                    int row = rf * 16 + ar;
                    int byte = (row * 2048 + 1024 + (kf * 32 + ks) * 2) ^ ((row & 7) << 4);
                    afF[rf] = *reinterpret_cast<const bf16x8*>(h1base + byte);
                }
            }
#pragma unroll
            for (int cf = 0; cf < 6; ++cf) {
                const bool hf = (colbase + cf * 16) >= 256;
                int col = colbase + cf * 16 + ar;
                bf16x8 bfr = *reinterpret_cast<const bf16x8*>(
                    &W2T[(size_t)col * 512 + kf * 32 + ks]);
#pragma unroll
                for (int rf = 0; rf < 2; ++rf)
                    acc[rf][cf] = __builtin_amdgcn_mfma_f32_16x16x32_bf16(
                        hf ? afF[rf] : afP[rf], bfr, acc[rf][cf], 0, 0, 0);
            }
        }

        // ---------------- head readout ----------------
#pragma unroll
        for (int rf = 0; rf < 2; ++rf) {
            float hsp[4] = {0.f, 0.f, 0.f, 0.f};
            float hsf[4] = {0.f, 0.f, 0.f, 0.f};
            float hse[4] = {0.f, 0.f, 0.f, 0.f};
#pragma unroll
            for (int cf = 0; cf < 6; ++cf) {
                const int colc = colbase + cf * 16;
                const int col = colc + ar;
                const float b2 = bias2[col];
                if (colc < 256) {
                    const float w3 = pw3[col];
#pragma unroll
                    for (int g = 0; g < 4; ++g) {
                        float h = gelu_fast(acc[rf][cf][g] + b2);
                        hsp[g] += h * w3;
                    }
                } else {
                    const float wf = fw3[(col - 256) * 2];
                    const float we = fw3[(col - 256) * 2 + 1];
#pragma unroll
                    for (int g = 0; g < 4; ++g) {
                        float h = gelu_fast(acc[rf][cf][g] + b2);
                        hsf[g] += h * wf;
                        hse[g] += h * we;
                    }
                }
            }
#pragma unroll
            for (int g = 0; g < 4; ++g) {
                float a = hsp[g], b = hsf[g], c = hse[g];
#pragma unroll
                for (int m = 1; m < 16; m <<= 1) {
                    a += __shfl_xor(a, m);
                    b += __shfl_xor(b, m);
                    c += __shfl_xor(c, m);
                }
                if ((l & 15) == 0) {
                    int row = rf * 16 + (l >> 4) * 4 + g;
                    redh[wv][row][0] = a;
                    redh[wv][row][1] = b;
                    redh[wv][row][2] = c;
                }
            }
        }
        __syncthreads();

        // ---------------- tail (wave 0, lanes 0..31) ----------------
        if (wv == 0 && l < 32) {
            const int row = l;
            const int b = row0 + row;
            float sp = 0.f, sf = 0.f, se = 0.f;
#pragma unroll
            for (int w2 = 0; w2 < 8; ++w2) {
                sp += redh[w2][row][0];
                sf += redh[w2][row][1];
                se += redh[w2][row][2];
            }
            float logit = sp + pb3[0];
            float pf    = sf + fb3[0];
            float pe    = se + fb3[1];
            int ridx = rid_s[row];
            float gt_f = freq[b * 3 + ridx];
            float gt_p = presv[b * 3 + ridx];
            float gt_e = enrich[b * 3 + ridx];
            float m = (float)round_mask[b * 3 + ridx];
            lf_acc  += (pf - gt_f) * (pf - gt_f) * m;
            bce_acc += (fmaxf(logit, 0.f) - logit * gt_p + log1pf(expf(-fabsf(logit)))) * m;
            le_acc  += (pe - gt_e) * (pe - gt_e) * m;
            mm_acc  += m;
            bool msk = m > 0.5f;
            float act_f = msk ? fminf(fmaxf(pf, -10.f), 10.f) : gt_f;
            float act_p = msk ? 1.f / (1.f + expf(-logit)) : gt_p;
            float act_e = msk ? fminf(fmaxf(pe, -100.f), 100.f) : gt_e;
            state_s[row][ridx * 2 + 0] = act_p;
            state_s[row][ridx * 2 + 1] = 1.f;
            state_s[row][8 + ridx * 4 + 0] = act_f;
            state_s[row][8 + ridx * 4 + 1] = act_p;
            state_s[row][8 + ridx * 4 + 2] = act_e;
            state_s[row][8 + ridx * 4 + 3] = 1.f;
            out[3 + b * 3 + ridx] = act_f;
            out[3 + 3 * BATCH + b * 3 + ridx] = act_p;
            out[3 + 6 * BATCH + b * 3 + ridx] = act_e;
            if (step < 2) rid_s[row] = PERMS_C[pidx_s[row]][step + 1];
        }
        __syncthreads();
    }

    // ---- per-block loss partials ----
    if (wv == 0) {
        for (int off = 32; off > 0; off >>= 1) {
            lf_acc  += __shfl_down(lf_acc, off);
            bce_acc += __shfl_down(bce_acc, off);
            le_acc  += __shfl_down(le_acc, off);
            mm_acc  += __shfl_down(mm_acc, off);
        }
        if (l == 0) {
            float4 v; v.x = lf_acc; v.y = bce_acc; v.z = le_acc; v.w = mm_acc;
            *reinterpret_cast<float4*>(&part[blockIdx.x * 4]) = v;
        }
    }
}

#define NPART (BATCH / 32)

__global__ __launch_bounds__(256) void finalize_kernel(
    const float* __restrict__ part, float* __restrict__ out)
{
    __shared__ float red[4][4];
    float a0 = 0.f, a1 = 0.f, a2 = 0.f, a3 = 0.f;
    for (int j = threadIdx.x; j < NPART; j += 256) {
        float4 v = *reinterpret_cast<const float4*>(&part[j * 4]);
        a0 += v.x; a1 += v.y; a2 += v.z; a3 += v.w;
    }
    for (int off = 32; off > 0; off >>= 1) {
        a0 += __shfl_down(a0, off);
        a1 += __shfl_down(a1, off);
        a2 += __shfl_down(a2, off);
        a3 += __shfl_down(a3, off);
    }
    const int wid = threadIdx.x >> 6, lane = threadIdx.x & 63;
    if (lane == 0) { red[wid][0] = a0; red[wid][1] = a1; red[wid][2] = a2; red[wid][3] = a3; }
    __syncthreads();
    if (threadIdx.x == 0) {
        float s0 = 0.f, s1 = 0.f, s2 = 0.f, s3 = 0.f;
#pragma unroll
        for (int w2 = 0; w2 < 4; ++w2) {
            s0 += red[w2][0]; s1 += red[w2][1]; s2 += red[w2][2]; s3 += red[w2][3];
        }
        float nm = s3 + 1e-8f;
        out[0] = s0 / nm;
        out[1] = s1 / nm;
        out[2] = s2 / nm;
    }
}

// ---------------------------------------------------------------------------
extern "C" void kernel_launch(void* const* d_in, const int* in_sizes, int n_in,
                              void* d_out, int out_size, void* d_ws, size_t ws_size,
                              hipStream_t stream)
{
    const float* seq       = (const float*)d_in[0];
    const float* freq      = (const float*)d_in[1];
    const float* presv     = (const float*)d_in[2];
    const float* enrich    = (const float*)d_in[3];
    const float* pw1       = (const float*)d_in[4];
    const float* pb1       = (const float*)d_in[5];
    const float* pw2       = (const float*)d_in[6];
    const float* pb2       = (const float*)d_in[7];
    const float* pw3       = (const float*)d_in[8];
    const float* pb3       = (const float*)d_in[9];
    const float* fw1       = (const float*)d_in[10];
    const float* fb1       = (const float*)d_in[11];
    const float* fw2       = (const float*)d_in[12];
    const float* fb2       = (const float*)d_in[13];
    const float* fw3       = (const float*)d_in[14];
    const float* fb3       = (const float*)d_in[15];
    const int*   perm_idx  = (const int*)d_in[16];
    const int*   round_mask= (const int*)d_in[17];
    float* out = (float*)d_out;

    char* w = (char*)d_ws;
    u16* sb  = (u16*)w;  w += (size_t)BATCH * 512 * 2;   // 16 MB
    u16* Z   = (u16*)w;  w += (size_t)BATCH * 1024 * 2;  // 32 MB
    u16* W1T = (u16*)w;  w += (size_t)1024 * 512 * 2;
    u16* W2T = (u16*)w;  w += (size_t)768 * 512 * 2;
    float* bias1 = (float*)w; w += 1024 * 4;
    float* bias2 = (float*)w; w += 768 * 4;
    float* part  = (float*)w;

    // prep
    {
        const int total = BATCH * 512 + 1024 * 512 + 768 * 512 + 1024 + 768;
        int grid = (total + 255) / 256;
        prep_kernel<<<grid, 256, 0, stream>>>(seq, pw1, pw2, fw1, fw2, pb1, pb2, fb1, fb2,
                                              sb, W1T, W2T, bias1, bias2);
    }

    // Z = seq @ [pw1[:512] | fw1[:512]] + bias1   (M=16384, N=1024, K=512)
    gemm_bf16<<<dim3(BATCH / 128, 1024 / 128), 256, 0, stream>>>(
        sb, 512, W1T, bias1, Z, BATCH, 1024, 512);

    // fused 3-step decode: 512 blocks x 512 threads (2 blocks/CU)
    decode3<<<NPART, 512, 0, stream>>>(
        Z, pw1 + (size_t)512 * 512, fw1 + (size_t)512 * 512,
        W2T, bias2, pw3, pb3, fw3, fb3,
        freq, presv, enrich, round_mask, perm_idx, part, out);

    finalize_kernel<<<1, 256, 0, stream>>>(part, out);
}

// Round 10
// 448.858 us; speedup vs baseline: 1.0153x; 1.0153x over previous
//
#include <hip/hip_runtime.h>
#include <hip/hip_bf16.h>
#include <math.h>

#define BATCH 16384

typedef unsigned short u16;
typedef short bf16x8 __attribute__((ext_vector_type(8)));
typedef float f32x4 __attribute__((ext_vector_type(4)));
typedef u16 u16x8 __attribute__((ext_vector_type(8)));
typedef u16 u16x2 __attribute__((ext_vector_type(2)));

__constant__ int PERMS_C[6][3] = {{0,1,2},{0,2,1},{1,0,2},{1,2,0},{2,0,1},{2,1,0}};

__device__ inline float bf2f(u16 u) {
    unsigned int x = ((unsigned int)u) << 16;
    float f; __builtin_memcpy(&f, &x, 4); return f;
}
__device__ inline u16 f2bf(float f) {
    __hip_bfloat16 h = __float2bfloat16(f);
    u16 u; __builtin_memcpy(&u, &h, 2); return u;
}
// tanh-approx gelu: x * sigmoid(1.5957691x + 0.0713548x^3). |err| ~3e-4,
// below the bf16 rounding already applied to H1/H2 values.
__device__ __forceinline__ float gelu_fast(float x) {
    float t = x * (1.59576912f + x * x * 0.07135481f);
    return x / (1.0f + __expf(-t));
}

// async global->LDS, 16B per lane, wave-uniform LDS base + lane*16
__device__ inline void gload_lds16(const u16* g, u16* l) {
    __builtin_amdgcn_global_load_lds(
        (const __attribute__((address_space(1))) unsigned int*)g,
        (__attribute__((address_space(3))) unsigned int*)l,
        16, 0, 0);
}

// ---------------------------------------------------------------------------
// prep: convert seq_embed to bf16, build transposed bf16 weight blocks,
// concatenated biases.
// ---------------------------------------------------------------------------
__global__ __launch_bounds__(256) void prep_kernel(
    const float* __restrict__ seq,
    const float* __restrict__ pw1, const float* __restrict__ pw2,
    const float* __restrict__ fw1, const float* __restrict__ fw2,
    const float* __restrict__ pb1, const float* __restrict__ pb2,
    const float* __restrict__ fb1, const float* __restrict__ fb2,
    u16* __restrict__ sb, u16* __restrict__ W1T, u16* __restrict__ W2T,
    float* __restrict__ bias1, float* __restrict__ bias2)
{
    const int N0 = BATCH * 512;      // seq conversion
    const int N1 = 1024 * 512;       // W1T
    const int N2 = 768 * 512;        // W2T
    const int N3 = 1024;             // bias1
    const int N4 = 768;              // bias2
    int i = blockIdx.x * 256 + threadIdx.x;
    if (i < N0) { sb[i] = f2bf(seq[i]); return; }
    i -= N0;
    if (i < N1) {
        int n = i >> 9, k = i & 511;
        float v = (n < 512) ? pw1[(size_t)k * 512 + n] : fw1[(size_t)k * 512 + (n - 512)];
        W1T[i] = f2bf(v); return;
    }
    i -= N1;
    if (i < N2) {
        int n = i >> 9, k = i & 511;
        float v = (n < 256) ? pw2[(size_t)k * 256 + n] : fw2[(size_t)k * 512 + (n - 256)];
        W2T[i] = f2bf(v); return;
    }
    i -= N2;
    if (i < N3) { bias1[i] = (i < 512) ? pb1[i] : fb1[i - 512]; return; }
    i -= N3;
    if (i < N4) { bias2[i] = (i < 256) ? pb2[i] : fb2[i - 256]; return; }
}

// ---------------------------------------------------------------------------
// bf16 MFMA GEMM: C[M,N](bf16) = A[M,K] @ Bt[N,K]^T + bias.
// 128x128 tile, 4 waves, BK=64, global_load_lds staging, linear LDS.
// Used only for Z = seq @ [pw1|fw1] + bias1.
// ---------------------------------------------------------------------------
__global__ __launch_bounds__(256) void gemm_bf16(
    const u16* __restrict__ A, int lda,
    const u16* __restrict__ Bt, const float* __restrict__ bias,
    u16* __restrict__ C, int M, int N, int K)
{
    __shared__ __align__(16) u16 As[128 * 64];
    __shared__ __align__(16) u16 Bs[128 * 64];

    const int bm = blockIdx.x * 128;
    const int bn = blockIdx.y * 128;

    const int tid = threadIdx.x;
    const int wv = tid >> 6;
    const int lane = tid & 63;
    const int wr = wv >> 1;
    const int wc = wv & 1;

    const int lrow = lane >> 3;
    const int lcol = (lane & 7) << 3;

    f32x4 acc[4][4];
#pragma unroll
    for (int i = 0; i < 4; ++i)
#pragma unroll
        for (int j = 0; j < 4; ++j) acc[i][j] = (f32x4){0.f, 0.f, 0.f, 0.f};

    for (int k0 = 0; k0 < K; k0 += 64) {
#pragma unroll
        for (int q = 0; q < 4; ++q) {
            const int c = wv * 4 + q;
            const int row = c * 8 + lrow;
            gload_lds16(&A[(size_t)(bm + row) * lda + k0 + lcol], &As[c * 512]);
            gload_lds16(&Bt[(size_t)(bn + row) * K + k0 + lcol], &Bs[c * 512]);
        }
        __syncthreads();

#pragma unroll
        for (int ks = 0; ks < 64; ks += 32) {
            int kk = ks + (lane >> 4) * 8;
            bf16x8 af[4], bfr[4];
#pragma unroll
            for (int i = 0; i < 4; ++i)
                af[i] = *reinterpret_cast<const bf16x8*>(&As[(wr * 64 + i * 16 + (lane & 15)) * 64 + kk]);
#pragma unroll
            for (int j = 0; j < 4; ++j)
                bfr[j] = *reinterpret_cast<const bf16x8*>(&Bs[(wc * 64 + j * 16 + (lane & 15)) * 64 + kk]);
#pragma unroll
            for (int i = 0; i < 4; ++i)
#pragma unroll
                for (int j = 0; j < 4; ++j)
                    acc[i][j] = __builtin_amdgcn_mfma_f32_16x16x32_bf16(af[i], bfr[j], acc[i][j], 0, 0, 0);
        }
        __syncthreads();
    }

    const int r4 = (lane >> 4) * 4;
    const int cn = lane & 15;
#pragma unroll
    for (int i = 0; i < 4; ++i) {
#pragma unroll
        for (int j = 0; j < 4; ++j) {
            int gcol = bn + wc * 64 + j * 16 + cn;
            float bsv = bias[gcol];
#pragma unroll
            for (int r = 0; r < 4; ++r) {
                int grow = bm + wr * 64 + i * 16 + r4 + r;
                C[(size_t)grow * N + gcol] = f2bf(acc[i][j][r] + bsv);
            }
        }
    }
}

// ---------------------------------------------------------------------------
// decode3 v4: fused 3-step decode. 32 rows/block, 1024 threads (16 waves),
// 512 blocks (1 block/CU). Z slice staged to LDS ONCE via global_load_lds
// (contiguous 64 KB) -- no per-thread arrays live across phases, so nothing
// spills at the compiler's 64-VGPR target (R7/R9 failure mode eliminated).
// ---------------------------------------------------------------------------

template<int NS>
__device__ __forceinline__ void h1_phase(
    const float* __restrict__ wsrc, int cw0, int rg,
    const u16* __restrict__ Zs, int gcol0, char* h1base,
    const float (*state)[20], const int* rid)
{
    float w[NS + 3][2];
#pragma unroll
    for (int r = 0; r < NS + 3; ++r) {
        float2 v = *reinterpret_cast<const float2*>(&wsrc[(size_t)r * 512 + cw0]);
        w[r][0] = v.x; w[r][1] = v.y;
    }
#pragma unroll
    for (int r = 0; r < 16; ++r) {
        const int row = rg * 16 + r;
        const int ridx = rid[row];
        float s[NS];
        if constexpr (NS == 6) {
            float4 a = *reinterpret_cast<const float4*>(&state[row][0]);
            float2 b = *reinterpret_cast<const float2*>(&state[row][4]);
            s[0] = a.x; s[1] = a.y; s[2] = a.z; s[3] = a.w; s[4] = b.x; s[5] = b.y;
        } else {
            float4 a = *reinterpret_cast<const float4*>(&state[row][8]);
            float4 b = *reinterpret_cast<const float4*>(&state[row][12]);
            float4 c = *reinterpret_cast<const float4*>(&state[row][16]);
            s[0] = a.x; s[1] = a.y; s[2]  = a.z; s[3]  = a.w;
            s[4] = b.x; s[5] = b.y; s[6]  = b.z; s[7]  = b.w;
            s[8] = c.x; s[9] = c.y; s[10] = c.z; s[11] = c.w;
        }
        u16x2 z = *reinterpret_cast<const u16x2*>(&Zs[row * 1024 + gcol0]);
        float d0 = (ridx == 0) ? w[NS][0] : ((ridx == 1) ? w[NS + 1][0] : w[NS + 2][0]);
        float d1 = (ridx == 0) ? w[NS][1] : ((ridx == 1) ? w[NS + 1][1] : w[NS + 2][1]);
#pragma unroll
        for (int j = 0; j < NS; ++j) { d0 += s[j] * w[j][0]; d1 += s[j] * w[j][1]; }
        float h0 = gelu_fast(bf2f(z[0]) + d0);
        float h1 = gelu_fast(bf2f(z[1]) + d1);
        unsigned int packed = (unsigned int)f2bf(h0) | ((unsigned int)f2bf(h1) << 16);
        int byte = (row * 2048 + gcol0 * 2) ^ ((row & 7) << 4);
        *reinterpret_cast<unsigned int*>(h1base + byte) = packed;
    }
}

__global__ __launch_bounds__(1024, 4) void decode3(
    const u16* __restrict__ Z,
    const float* __restrict__ pw1s, const float* __restrict__ fw1s,
    const u16* __restrict__ W2T, const float* __restrict__ bias2,
    const float* __restrict__ pw3, const float* __restrict__ pb3,
    const float* __restrict__ fw3, const float* __restrict__ fb3,
    const float* __restrict__ freq, const float* __restrict__ presv,
    const float* __restrict__ enrich, const int* __restrict__ round_mask,
    const int* __restrict__ perm_idx,
    float* __restrict__ part, float* __restrict__ out)
{
    __shared__ __align__(16) u16 Zs[32 * 1024];    // 64 KB, linear
    __shared__ __align__(16) u16 H1s[32 * 1024];   // 64 KB, XOR-swizzled
    __shared__ float redh[16][32][3];              // 6 KB
    __shared__ __align__(16) float state_s[32][20];// [0:6) pres, [8:20) full
    __shared__ int pidx_s[32];
    __shared__ int rid_s[32];

    const int tid = threadIdx.x;
    const int wv  = tid >> 6;   // 0..15
    const int l   = tid & 63;
    const int row0 = blockIdx.x * 32;

    // H1-phase thread geometry: thread = (col pair, 16-row group)
    const int ci    = tid & 511;      // column pair index (0..511)
    const int rg    = tid >> 9;       // row group (0/1): rows rg*16..rg*16+15
    const int half  = ci >> 8;        // 0 = pres cols, 1 = full cols
    const int cw0   = (ci & 255) * 2; // col within half
    const int gcol0 = ci * 2;         // global H1 col
    char* h1base = reinterpret_cast<char*>(H1s);

    // ---- stage Z slice (contiguous 64 KB) into LDS, once ----
    {
        const u16* zsrc = Z + (size_t)row0 * 1024;
#pragma unroll
        for (int q = 0; q < 4; ++q) {
            const int c = wv * 4 + q;   // 64 chunks of 1 KB
            gload_lds16(zsrc + c * 512 + l * 8, &Zs[c * 512]);
        }
    }

    // ---- init state ----
    {
        float* ss = &state_s[0][0];
        for (int i = tid; i < 32 * 20; i += 1024) ss[i] = 0.f;
        if (tid < 32) {
            int pp = perm_idx[row0 + tid];
            pidx_s[tid] = pp;
            rid_s[tid] = PERMS_C[pp][0];
        }
    }
    __syncthreads();   // drains the global_load_lds too

    // H2-phase wave geometry: wave wv covers cols [wv*48, wv*48+48)
    const int colbase = wv * 48;
    const bool needP = (colbase < 256);
    const bool needF = (colbase + 32) >= 256;

    float lf_acc = 0.f, bce_acc = 0.f, le_acc = 0.f, mm_acc = 0.f;

#pragma unroll 1
    for (int step = 0; step < 3; ++step) {
        // ---------------- H1 phase ----------------
        if (half == 0)
            h1_phase<6>(pw1s, cw0, rg, Zs, gcol0, h1base, state_s, rid_s);
        else
            h1_phase<12>(fw1s, cw0, rg, Zs, gcol0, h1base, state_s, rid_s);
        __syncthreads();

        // ---------------- H2 GEMM ----------------
        f32x4 acc[2][3];
#pragma unroll
        for (int rf = 0; rf < 2; ++rf)
#pragma unroll
            for (int cf = 0; cf < 3; ++cf) acc[rf][cf] = (f32x4){0.f, 0.f, 0.f, 0.f};

        const int ar = l & 15;
        const int ks = (l >> 4) * 8;
#pragma unroll 2
        for (int kf = 0; kf < 16; ++kf) {
            bf16x8 afP[2], afF[2];
            if (needP) {
#pragma unroll
                for (int rf = 0; rf < 2; ++rf) {
                    int row = rf * 16 + ar;
                    int byte = (row * 2048 + (kf * 32 + ks) * 2) ^ ((row & 7) << 4);
                    afP[rf] = *reinterpret_cast<const bf16x8*>(h1base + byte);
                }
            }
            if (needF) {
#pragma unroll
                for (int rf = 0; rf < 2; ++rf) {
                    int row = rf * 16 + ar;
                    int byte = (row * 2048 + 1024 + (kf * 32 + ks) * 2) ^ ((row & 7) << 4);
                    afF[rf] = *reinterpret_cast<const bf16x8*>(h1base + byte);
                }
            }
#pragma unroll
            for (int cf = 0; cf < 3; ++cf) {
                const bool hf = (colbase + cf * 16) >= 256;
                int col = colbase + cf * 16 + ar;
                bf16x8 bfr = *reinterpret_cast<const bf16x8*>(
                    &W2T[(size_t)col * 512 + kf * 32 + ks]);
#pragma unroll
                for (int rf = 0; rf < 2; ++rf)
                    acc[rf][cf] = __builtin_amdgcn_mfma_f32_16x16x32_bf16(
                        hf ? afF[rf] : afP[rf], bfr, acc[rf][cf], 0, 0, 0);
            }
        }

        // ---------------- head readout ----------------
#pragma unroll
        for (int rf = 0; rf < 2; ++rf) {
            float hsp[4] = {0.f, 0.f, 0.f, 0.f};
            float hsf[4] = {0.f, 0.f, 0.f, 0.f};
            float hse[4] = {0.f, 0.f, 0.f, 0.f};
#pragma unroll
            for (int cf = 0; cf < 3; ++cf) {
                const int colc = colbase + cf * 16;
                const int col = colc + ar;
                const float b2 = bias2[col];
                if (colc < 256) {
                    const float w3 = pw3[col];
#pragma unroll
                    for (int g = 0; g < 4; ++g) {
                        float h = gelu_fast(acc[rf][cf][g] + b2);
                        hsp[g] += h * w3;
                    }
                } else {
                    const float wf = fw3[(col - 256) * 2];
                    const float we = fw3[(col - 256) * 2 + 1];
#pragma unroll
                    for (int g = 0; g < 4; ++g) {
                        float h = gelu_fast(acc[rf][cf][g] + b2);
                        hsf[g] += h * wf;
                        hse[g] += h * we;
                    }
                }
            }
#pragma unroll
            for (int g = 0; g < 4; ++g) {
                float a = hsp[g], b = hsf[g], c = hse[g];
#pragma unroll
                for (int m = 1; m < 16; m <<= 1) {
                    a += __shfl_xor(a, m);
                    b += __shfl_xor(b, m);
                    c += __shfl_xor(c, m);
                }
                if ((l & 15) == 0) {
                    int row = rf * 16 + (l >> 4) * 4 + g;
                    redh[wv][row][0] = a;
                    redh[wv][row][1] = b;
                    redh[wv][row][2] = c;
                }
            }
        }
        __syncthreads();

        // ---------------- tail (wave 0, lanes 0..31) ----------------
        if (wv == 0 && l < 32) {
            const int row = l;
            const int b = row0 + row;
            float sp = 0.f, sf = 0.f, se = 0.f;
#pragma unroll
            for (int w2 = 0; w2 < 16; ++w2) {
                sp += redh[w2][row][0];
                sf += redh[w2][row][1];
                se += redh[w2][row][2];
            }
            float logit = sp + pb3[0];
            float pf    = sf + fb3[0];
            float pe    = se + fb3[1];
            int ridx = rid_s[row];
            float gt_f = freq[b * 3 + ridx];
            float gt_p = presv[b * 3 + ridx];
            float gt_e = enrich[b * 3 + ridx];
            float m = (float)round_mask[b * 3 + ridx];
            lf_acc  += (pf - gt_f) * (pf - gt_f) * m;
            bce_acc += (fmaxf(logit, 0.f) - logit * gt_p + log1pf(expf(-fabsf(logit)))) * m;
            le_acc  += (pe - gt_e) * (pe - gt_e) * m;
            mm_acc  += m;
            bool msk = m > 0.5f;
            float act_f = msk ? fminf(fmaxf(pf, -10.f), 10.f) : gt_f;
            float act_p = msk ? 1.f / (1.f + expf(-logit)) : gt_p;
            float act_e = msk ? fminf(fmaxf(pe, -100.f), 100.f) : gt_e;
            state_s[row][ridx * 2 + 0] = act_p;
            state_s[row][ridx * 2 + 1] = 1.f;
            state_s[row][8 + ridx * 4 + 0] = act_f;
            state_s[row][8 + ridx * 4 + 1] = act_p;
            state_s[row][8 + ridx * 4 + 2] = act_e;
            state_s[row][8 + ridx * 4 + 3] = 1.f;
            out[3 + b * 3 + ridx] = act_f;
            out[3 + 3 * BATCH + b * 3 + ridx] = act_p;
            out[3 + 6 * BATCH + b * 3 + ridx] = act_e;
            if (step < 2) rid_s[row] = PERMS_C[pidx_s[row]][step + 1];
        }
        __syncthreads();
    }

    // ---- per-block loss partials ----
    if (wv == 0) {
        for (int off = 32; off > 0; off >>= 1) {
            lf_acc  += __shfl_down(lf_acc, off);
            bce_acc += __shfl_down(bce_acc, off);
            le_acc  += __shfl_down(le_acc, off);
            mm_acc  += __shfl_down(mm_acc, off);
        }
        if (l == 0) {
            float4 v; v.x = lf_acc; v.y = bce_acc; v.z = le_acc; v.w = mm_acc;
            *reinterpret_cast<float4*>(&part[blockIdx.x * 4]) = v;
        }
    }
}

#define NPART (BATCH / 32)

__global__ __launch_bounds__(256) void finalize_kernel(
    const float* __restrict__ part, float* __restrict__ out)
{
    __shared__ float red[4][4];
    float a0 = 0.f, a1 = 0.f, a2 = 0.f, a3 = 0.f;
    for (int j = threadIdx.x; j < NPART; j += 256) {
        float4 v = *reinterpret_cast<const float4*>(&part[j * 4]);
        a0 += v.x; a1 += v.y; a2 += v.z; a3 += v.w;
    }
    for (int off = 32; off > 0; off >>= 1) {
        a0 += __shfl_down(a0, off);
        a1 += __shfl_down(a1, off);
        a2 += __shfl_down(a2, off);
        a3 += __shfl_down(a3, off);
    }
    const int wid = threadIdx.x >> 6, lane = threadIdx.x & 63;
    if (lane == 0) { red[wid][0] = a0; red[wid][1] = a1; red[wid][2] = a2; red[wid][3] = a3; }
    __syncthreads();
    if (threadIdx.x == 0) {
        float s0 = 0.f, s1 = 0.f, s2 = 0.f, s3 = 0.f;
#pragma unroll
        for (int w2 = 0; w2 < 4; ++w2) {
            s0 += red[w2][0]; s1 += red[w2][1]; s2 += red[w2][2]; s3 += red[w2][3];
        }
        float nm = s3 + 1e-8f;
        out[0] = s0 / nm;
        out[1] = s1 / nm;
        out[2] = s2 / nm;
    }
}

// ---------------------------------------------------------------------------
extern "C" void kernel_launch(void* const* d_in, const int* in_sizes, int n_in,
                              void* d_out, int out_size, void* d_ws, size_t ws_size,
                              hipStream_t stream)
{
    const float* seq       = (const float*)d_in[0];
    const float* freq      = (const float*)d_in[1];
    const float* presv     = (const float*)d_in[2];
    const float* enrich    = (const float*)d_in[3];
    const float* pw1       = (const float*)d_in[4];
    const float* pb1       = (const float*)d_in[5];
    const float* pw2       = (const float*)d_in[6];
    const float* pb2       = (const float*)d_in[7];
    const float* pw3       = (const float*)d_in[8];
    const float* pb3       = (const float*)d_in[9];
    const float* fw1       = (const float*)d_in[10];
    const float* fb1       = (const float*)d_in[11];
    const float* fw2       = (const float*)d_in[12];
    const float* fb2       = (const float*)d_in[13];
    const float* fw3       = (const float*)d_in[14];
    const float* fb3       = (const float*)d_in[15];
    const int*   perm_idx  = (const int*)d_in[16];
    const int*   round_mask= (const int*)d_in[17];
    float* out = (float*)d_out;

    char* w = (char*)d_ws;
    u16* sb  = (u16*)w;  w += (size_t)BATCH * 512 * 2;   // 16 MB
    u16* Z   = (u16*)w;  w += (size_t)BATCH * 1024 * 2;  // 32 MB
    u16* W1T = (u16*)w;  w += (size_t)1024 * 512 * 2;
    u16* W2T = (u16*)w;  w += (size_t)768 * 512 * 2;
    float* bias1 = (float*)w; w += 1024 * 4;
    float* bias2 = (float*)w; w += 768 * 4;
    float* part  = (float*)w;

    // prep
    {
        const int total = BATCH * 512 + 1024 * 512 + 768 * 512 + 1024 + 768;
        int grid = (total + 255) / 256;
        prep_kernel<<<grid, 256, 0, stream>>>(seq, pw1, pw2, fw1, fw2, pb1, pb2, fb1, fb2,
                                              sb, W1T, W2T, bias1, bias2);
    }

    // Z = seq @ [pw1[:512] | fw1[:512]] + bias1   (M=16384, N=1024, K=512)
    gemm_bf16<<<dim3(BATCH / 128, 1024 / 128), 256, 0, stream>>>(
        sb, 512, W1T, bias1, Z, BATCH, 1024, 512);

    // fused 3-step decode: 512 blocks x 1024 threads, Z staged to LDS once
    decode3<<<NPART, 1024, 0, stream>>>(
        Z, pw1 + (size_t)512 * 512, fw1 + (size_t)512 * 512,
        W2T, bias2, pw3, pb3, fw3, fb3,
        freq, presv, enrich, round_mask, perm_idx, part, out);

    finalize_kernel<<<1, 256, 0, stream>>>(part, out);
}

// Round 11
// 434.709 us; speedup vs baseline: 1.0484x; 1.0325x over previous
//
#include <hip/hip_runtime.h>
#include <hip/hip_bf16.h>
#include <math.h>

#define BATCH 16384

typedef unsigned short u16;
typedef short bf16x8 __attribute__((ext_vector_type(8)));
typedef float f32x4 __attribute__((ext_vector_type(4)));
typedef u16 u16x8 __attribute__((ext_vector_type(8)));
typedef u16 u16x2 __attribute__((ext_vector_type(2)));

__constant__ int PERMS_C[6][3] = {{0,1,2},{0,2,1},{1,0,2},{1,2,0},{2,0,1},{2,1,0}};

__device__ inline float bf2f(u16 u) {
    unsigned int x = ((unsigned int)u) << 16;
    float f; __builtin_memcpy(&f, &x, 4); return f;
}
__device__ inline u16 f2bf(float f) {
    __hip_bfloat16 h = __float2bfloat16(f);
    u16 u; __builtin_memcpy(&u, &h, 2); return u;
}
// tanh-approx gelu: x * sigmoid(1.5957691x + 0.0713548x^3). |err| ~3e-4,
// below the bf16 rounding already applied to H1/H2 values.
__device__ __forceinline__ float gelu_fast(float x) {
    float t = x * (1.59576912f + x * x * 0.07135481f);
    return x / (1.0f + __expf(-t));
}

// async global->LDS, 16B per lane, wave-uniform LDS base + lane*16
__device__ inline void gload_lds16(const u16* g, u16* l) {
    __builtin_amdgcn_global_load_lds(
        (const __attribute__((address_space(1))) unsigned int*)g,
        (__attribute__((address_space(3))) unsigned int*)l,
        16, 0, 0);
}

// ---------------------------------------------------------------------------
// prep: convert seq_embed to bf16, build transposed bf16 weight blocks,
// concatenated biases.
// ---------------------------------------------------------------------------
__global__ __launch_bounds__(256) void prep_kernel(
    const float* __restrict__ seq,
    const float* __restrict__ pw1, const float* __restrict__ pw2,
    const float* __restrict__ fw1, const float* __restrict__ fw2,
    const float* __restrict__ pb1, const float* __restrict__ pb2,
    const float* __restrict__ fb1, const float* __restrict__ fb2,
    u16* __restrict__ sb, u16* __restrict__ W1T, u16* __restrict__ W2T,
    float* __restrict__ bias1, float* __restrict__ bias2)
{
    const int N0 = BATCH * 512;      // seq conversion
    const int N1 = 1024 * 512;       // W1T
    const int N2 = 768 * 512;        // W2T
    const int N3 = 1024;             // bias1
    const int N4 = 768;              // bias2
    int i = blockIdx.x * 256 + threadIdx.x;
    if (i < N0) { sb[i] = f2bf(seq[i]); return; }
    i -= N0;
    if (i < N1) {
        int n = i >> 9, k = i & 511;
        float v = (n < 512) ? pw1[(size_t)k * 512 + n] : fw1[(size_t)k * 512 + (n - 512)];
        W1T[i] = f2bf(v); return;
    }
    i -= N1;
    if (i < N2) {
        int n = i >> 9, k = i & 511;
        float v = (n < 256) ? pw2[(size_t)k * 256 + n] : fw2[(size_t)k * 512 + (n - 256)];
        W2T[i] = f2bf(v); return;
    }
    i -= N2;
    if (i < N3) { bias1[i] = (i < 512) ? pb1[i] : fb1[i - 512]; return; }
    i -= N3;
    if (i < N4) { bias2[i] = (i < 256) ? pb2[i] : fb2[i - 256]; return; }
}

// ---------------------------------------------------------------------------
// bf16 MFMA GEMM: C[M,N](bf16) = A[M,K] @ Bt[N,K]^T + bias.
// 128x128 tile, 4 waves, BK=64, global_load_lds staging, linear LDS.
// Used only for Z = seq @ [pw1|fw1] + bias1.
// ---------------------------------------------------------------------------
__global__ __launch_bounds__(256) void gemm_bf16(
    const u16* __restrict__ A, int lda,
    const u16* __restrict__ Bt, const float* __restrict__ bias,
    u16* __restrict__ C, int M, int N, int K)
{
    __shared__ __align__(16) u16 As[128 * 64];
    __shared__ __align__(16) u16 Bs[128 * 64];

    const int bm = blockIdx.x * 128;
    const int bn = blockIdx.y * 128;

    const int tid = threadIdx.x;
    const int wv = tid >> 6;
    const int lane = tid & 63;
    const int wr = wv >> 1;
    const int wc = wv & 1;

    const int lrow = lane >> 3;
    const int lcol = (lane & 7) << 3;

    f32x4 acc[4][4];
#pragma unroll
    for (int i = 0; i < 4; ++i)
#pragma unroll
        for (int j = 0; j < 4; ++j) acc[i][j] = (f32x4){0.f, 0.f, 0.f, 0.f};

    for (int k0 = 0; k0 < K; k0 += 64) {
#pragma unroll
        for (int q = 0; q < 4; ++q) {
            const int c = wv * 4 + q;
            const int row = c * 8 + lrow;
            gload_lds16(&A[(size_t)(bm + row) * lda + k0 + lcol], &As[c * 512]);
            gload_lds16(&Bt[(size_t)(bn + row) * K + k0 + lcol], &Bs[c * 512]);
        }
        __syncthreads();

#pragma unroll
        for (int ks = 0; ks < 64; ks += 32) {
            int kk = ks + (lane >> 4) * 8;
            bf16x8 af[4], bfr[4];
#pragma unroll
            for (int i = 0; i < 4; ++i)
                af[i] = *reinterpret_cast<const bf16x8*>(&As[(wr * 64 + i * 16 + (lane & 15)) * 64 + kk]);
#pragma unroll
            for (int j = 0; j < 4; ++j)
                bfr[j] = *reinterpret_cast<const bf16x8*>(&Bs[(wc * 64 + j * 16 + (lane & 15)) * 64 + kk]);
#pragma unroll
            for (int i = 0; i < 4; ++i)
#pragma unroll
                for (int j = 0; j < 4; ++j)
                    acc[i][j] = __builtin_amdgcn_mfma_f32_16x16x32_bf16(af[i], bfr[j], acc[i][j], 0, 0, 0);
        }
        __syncthreads();
    }

    const int r4 = (lane >> 4) * 4;
    const int cn = lane & 15;
#pragma unroll
    for (int i = 0; i < 4; ++i) {
#pragma unroll
        for (int j = 0; j < 4; ++j) {
            int gcol = bn + wc * 64 + j * 16 + cn;
            float bsv = bias[gcol];
#pragma unroll
            for (int r = 0; r < 4; ++r) {
                int grow = bm + wr * 64 + i * 16 + r4 + r;
                C[(size_t)grow * N + gcol] = f2bf(acc[i][j][r] + bsv);
            }
        }
    }
}

// ---------------------------------------------------------------------------
// decode3 v5: fused 3-step decode. 32 rows/block, 1024 threads (16 waves),
// 512 blocks, ~73 KB LDS -> 2 blocks/CU. No Z staging (L2/L3-resident reads,
// proven fine in R6). H2 k-loop split into a P-pass and an F-pass so only ONE
// A-fragment pair is live at a time -> H2 live regs ~58 < 64 -> no spill
// (R6-R10's ~300 B/thread scratch traffic eliminated).
// ---------------------------------------------------------------------------

template<int NS>
__device__ __forceinline__ void h1_phase(
    const float* __restrict__ wsrc, int cw0, int rg, int row0,
    const u16* __restrict__ Z, int gcol0, char* h1base,
    const float (*state)[20], const int* rid)
{
    float w[NS + 3][2];
#pragma unroll
    for (int r = 0; r < NS + 3; ++r) {
        float2 v = *reinterpret_cast<const float2*>(&wsrc[(size_t)r * 512 + cw0]);
        w[r][0] = v.x; w[r][1] = v.y;
    }
#pragma unroll 4
    for (int r = 0; r < 16; ++r) {
        const int row = rg * 16 + r;
        const int ridx = rid[row];
        float s[NS];
        if constexpr (NS == 6) {
            float4 a = *reinterpret_cast<const float4*>(&state[row][0]);
            float2 b = *reinterpret_cast<const float2*>(&state[row][4]);
            s[0] = a.x; s[1] = a.y; s[2] = a.z; s[3] = a.w; s[4] = b.x; s[5] = b.y;
        } else {
            float4 a = *reinterpret_cast<const float4*>(&state[row][8]);
            float4 b = *reinterpret_cast<const float4*>(&state[row][12]);
            float4 c = *reinterpret_cast<const float4*>(&state[row][16]);
            s[0] = a.x; s[1] = a.y; s[2]  = a.z; s[3]  = a.w;
            s[4] = b.x; s[5] = b.y; s[6]  = b.z; s[7]  = b.w;
            s[8] = c.x; s[9] = c.y; s[10] = c.z; s[11] = c.w;
        }
        u16x2 z = *reinterpret_cast<const u16x2*>(&Z[(size_t)(row0 + row) * 1024 + gcol0]);
        float d0 = (ridx == 0) ? w[NS][0] : ((ridx == 1) ? w[NS + 1][0] : w[NS + 2][0]);
        float d1 = (ridx == 0) ? w[NS][1] : ((ridx == 1) ? w[NS + 1][1] : w[NS + 2][1]);
#pragma unroll
        for (int j = 0; j < NS; ++j) { d0 += s[j] * w[j][0]; d1 += s[j] * w[j][1]; }
        float h0 = gelu_fast(bf2f(z[0]) + d0);
        float h1 = gelu_fast(bf2f(z[1]) + d1);
        unsigned int packed = (unsigned int)f2bf(h0) | ((unsigned int)f2bf(h1) << 16);
        int byte = (row * 2048 + gcol0 * 2) ^ ((row & 7) << 4);
        *reinterpret_cast<unsigned int*>(h1base + byte) = packed;
    }
}

__global__ __launch_bounds__(1024) void decode3(
    const u16* __restrict__ Z,
    const float* __restrict__ pw1s, const float* __restrict__ fw1s,
    const u16* __restrict__ W2T, const float* __restrict__ bias2,
    const float* __restrict__ pw3, const float* __restrict__ pb3,
    const float* __restrict__ fw3, const float* __restrict__ fb3,
    const float* __restrict__ freq, const float* __restrict__ presv,
    const float* __restrict__ enrich, const int* __restrict__ round_mask,
    const int* __restrict__ perm_idx,
    float* __restrict__ part, float* __restrict__ out)
{
    __shared__ __align__(16) u16 H1s[32 * 1024];   // 64 KB, XOR-swizzled
    __shared__ float redh[16][32][3];              // 6 KB
    __shared__ __align__(16) float state_s[32][20];// [0:6) pres, [8:20) full
    __shared__ int pidx_s[32];
    __shared__ int rid_s[32];

    const int tid = threadIdx.x;
    const int wv  = tid >> 6;   // 0..15
    const int l   = tid & 63;
    const int row0 = blockIdx.x * 32;

    // H1-phase thread geometry: thread = (col pair, 16-row group)
    const int ci    = tid & 511;      // column pair index (0..511)
    const int rg    = tid >> 9;       // row group (0/1)
    const int half  = ci >> 8;        // 0 = pres cols, 1 = full cols (wave-uniform)
    const int cw0   = (ci & 255) * 2; // col within half
    const int gcol0 = ci * 2;         // global H1 col
    char* h1base = reinterpret_cast<char*>(H1s);

    // ---- init state ----
    {
        float* ss = &state_s[0][0];
        for (int i = tid; i < 32 * 20; i += 1024) ss[i] = 0.f;
        if (tid < 32) {
            int pp = perm_idx[row0 + tid];
            pidx_s[tid] = pp;
            rid_s[tid] = PERMS_C[pp][0];
        }
    }
    __syncthreads();

    // H2-phase wave geometry: wave wv covers cols [wv*48, wv*48+48)
    const int colbase = wv * 48;
    const bool needP = (colbase < 256);
    const bool needF = (colbase + 32) >= 256;

    float lf_acc = 0.f, bce_acc = 0.f, le_acc = 0.f, mm_acc = 0.f;

#pragma unroll 1
    for (int step = 0; step < 3; ++step) {
        asm volatile("" ::: "memory");   // keep w[] loads inside the step loop
        // ---------------- H1 phase ----------------
        if (half == 0)
            h1_phase<6>(pw1s, cw0, rg, row0, Z, gcol0, h1base, state_s, rid_s);
        else
            h1_phase<12>(fw1s, cw0, rg, row0, Z, gcol0, h1base, state_s, rid_s);
        __syncthreads();

        // ---------------- H2 GEMM (P-pass then F-pass, low pressure) -------
        f32x4 acc[2][3];
#pragma unroll
        for (int rf = 0; rf < 2; ++rf)
#pragma unroll
            for (int cf = 0; cf < 3; ++cf) acc[rf][cf] = (f32x4){0.f, 0.f, 0.f, 0.f};

        const int ar = l & 15;
        const int ks = (l >> 4) * 8;
        const int swz = (ar & 7) << 4;

        if (needP) {
            for (int kf = 0; kf < 16; ++kf) {
                const int kb = (kf * 32 + ks) * 2;
                bf16x8 af0 = *reinterpret_cast<const bf16x8*>(
                    h1base + ((ar * 2048 + kb) ^ swz));
                bf16x8 af1 = *reinterpret_cast<const bf16x8*>(
                    h1base + (((16 + ar) * 2048 + kb) ^ swz));
#pragma unroll
                for (int cf = 0; cf < 3; ++cf) {
                    if (colbase + cf * 16 < 256) {
                        int col = colbase + cf * 16 + ar;
                        bf16x8 bfr = *reinterpret_cast<const bf16x8*>(
                            &W2T[(size_t)col * 512 + kf * 32 + ks]);
                        acc[0][cf] = __builtin_amdgcn_mfma_f32_16x16x32_bf16(af0, bfr, acc[0][cf], 0, 0, 0);
                        acc[1][cf] = __builtin_amdgcn_mfma_f32_16x16x32_bf16(af1, bfr, acc[1][cf], 0, 0, 0);
                    }
                }
            }
        }
        if (needF) {
            for (int kf = 0; kf < 16; ++kf) {
                const int kb = 1024 + (kf * 32 + ks) * 2;
                bf16x8 af0 = *reinterpret_cast<const bf16x8*>(
                    h1base + ((ar * 2048 + kb) ^ swz));
                bf16x8 af1 = *reinterpret_cast<const bf16x8*>(
                    h1base + (((16 + ar) * 2048 + kb) ^ swz));
#pragma unroll
                for (int cf = 0; cf < 3; ++cf) {
                    if (colbase + cf * 16 >= 256) {
                        int col = colbase + cf * 16 + ar;
                        bf16x8 bfr = *reinterpret_cast<const bf16x8*>(
                            &W2T[(size_t)col * 512 + kf * 32 + ks]);
                        acc[0][cf] = __builtin_amdgcn_mfma_f32_16x16x32_bf16(af0, bfr, acc[0][cf], 0, 0, 0);
                        acc[1][cf] = __builtin_amdgcn_mfma_f32_16x16x32_bf16(af1, bfr, acc[1][cf], 0, 0, 0);
                    }
                }
            }
        }

        // ---------------- head readout ----------------
#pragma unroll
        for (int rf = 0; rf < 2; ++rf) {
            float hsp[4] = {0.f, 0.f, 0.f, 0.f};
            float hsf[4] = {0.f, 0.f, 0.f, 0.f};
            float hse[4] = {0.f, 0.f, 0.f, 0.f};
#pragma unroll
            for (int cf = 0; cf < 3; ++cf) {
                const int colc = colbase + cf * 16;
                const int col = colc + ar;
                const float b2 = bias2[col];
                if (colc < 256) {
                    const float w3 = pw3[col];
#pragma unroll
                    for (int g = 0; g < 4; ++g) {
                        float h = gelu_fast(acc[rf][cf][g] + b2);
                        hsp[g] += h * w3;
                    }
                } else {
                    const float wf = fw3[(col - 256) * 2];
                    const float we = fw3[(col - 256) * 2 + 1];
#pragma unroll
                    for (int g = 0; g < 4; ++g) {
                        float h = gelu_fast(acc[rf][cf][g] + b2);
                        hsf[g] += h * wf;
                        hse[g] += h * we;
                    }
                }
            }
#pragma unroll
            for (int g = 0; g < 4; ++g) {
                float a = hsp[g], b = hsf[g], c = hse[g];
#pragma unroll
                for (int m = 1; m < 16; m <<= 1) {
                    a += __shfl_xor(a, m);
                    b += __shfl_xor(b, m);
                    c += __shfl_xor(c, m);
                }
                if ((l & 15) == 0) {
                    int row = rf * 16 + (l >> 4) * 4 + g;
                    redh[wv][row][0] = a;
                    redh[wv][row][1] = b;
                    redh[wv][row][2] = c;
                }
            }
        }
        __syncthreads();

        // ---------------- tail (wave 0, lanes 0..31) ----------------
        if (wv == 0 && l < 32) {
            const int row = l;
            const int b = row0 + row;
            float sp = 0.f, sf = 0.f, se = 0.f;
#pragma unroll
            for (int w2 = 0; w2 < 16; ++w2) {
                sp += redh[w2][row][0];
                sf += redh[w2][row][1];
                se += redh[w2][row][2];
            }
            float logit = sp + pb3[0];
            float pf    = sf + fb3[0];
            float pe    = se + fb3[1];
            int ridx = rid_s[row];
            float gt_f = freq[b * 3 + ridx];
            float gt_p = presv[b * 3 + ridx];
            float gt_e = enrich[b * 3 + ridx];
            float m = (float)round_mask[b * 3 + ridx];
            lf_acc  += (pf - gt_f) * (pf - gt_f) * m;
            bce_acc += (fmaxf(logit, 0.f) - logit * gt_p + log1pf(expf(-fabsf(logit)))) * m;
            le_acc  += (pe - gt_e) * (pe - gt_e) * m;
            mm_acc  += m;
            bool msk = m > 0.5f;
            float act_f = msk ? fminf(fmaxf(pf, -10.f), 10.f) : gt_f;
            float act_p = msk ? 1.f / (1.f + expf(-logit)) : gt_p;
            float act_e = msk ? fminf(fmaxf(pe, -100.f), 100.f) : gt_e;
            state_s[row][ridx * 2 + 0] = act_p;
            state_s[row][ridx * 2 + 1] = 1.f;
            state_s[row][8 + ridx * 4 + 0] = act_f;
            state_s[row][8 + ridx * 4 + 1] = act_p;
            state_s[row][8 + ridx * 4 + 2] = act_e;
            state_s[row][8 + ridx * 4 + 3] = 1.f;
            out[3 + b * 3 + ridx] = act_f;
            out[3 + 3 * BATCH + b * 3 + ridx] = act_p;
            out[3 + 6 * BATCH + b * 3 + ridx] = act_e;
            if (step < 2) rid_s[row] = PERMS_C[pidx_s[row]][step + 1];
        }
        __syncthreads();
    }

    // ---- per-block loss partials ----
    if (wv == 0) {
        for (int off = 32; off > 0; off >>= 1) {
            lf_acc  += __shfl_down(lf_acc, off);
            bce_acc += __shfl_down(bce_acc, off);
            le_acc  += __shfl_down(le_acc, off);
            mm_acc  += __shfl_down(mm_acc, off);
        }
        if (l == 0) {
            float4 v; v.x = lf_acc; v.y = bce_acc; v.z = le_acc; v.w = mm_acc;
            *reinterpret_cast<float4*>(&part[blockIdx.x * 4]) = v;
        }
    }
}

#define NPART (BATCH / 32)

__global__ __launch_bounds__(256) void finalize_kernel(
    const float* __restrict__ part, float* __restrict__ out)
{
    __shared__ float red[4][4];
    float a0 = 0.f, a1 = 0.f, a2 = 0.f, a3 = 0.f;
    for (int j = threadIdx.x; j < NPART; j += 256) {
        float4 v = *reinterpret_cast<const float4*>(&part[j * 4]);
        a0 += v.x; a1 += v.y; a2 += v.z; a3 += v.w;
    }
    for (int off = 32; off > 0; off >>= 1) {
        a0 += __shfl_down(a0, off);
        a1 += __shfl_down(a1, off);
        a2 += __shfl_down(a2, off);
        a3 += __shfl_down(a3, off);
    }
    const int wid = threadIdx.x >> 6, lane = threadIdx.x & 63;
    if (lane == 0) { red[wid][0] = a0; red[wid][1] = a1; red[wid][2] = a2; red[wid][3] = a3; }
    __syncthreads();
    if (threadIdx.x == 0) {
        float s0 = 0.f, s1 = 0.f, s2 = 0.f, s3 = 0.f;
#pragma unroll
        for (int w2 = 0; w2 < 4; ++w2) {
            s0 += red[w2][0]; s1 += red[w2][1]; s2 += red[w2][2]; s3 += red[w2][3];
        }
        float nm = s3 + 1e-8f;
        out[0] = s0 / nm;
        out[1] = s1 / nm;
        out[2] = s2 / nm;
    }
}

// ---------------------------------------------------------------------------
extern "C" void kernel_launch(void* const* d_in, const int* in_sizes, int n_in,
                              void* d_out, int out_size, void* d_ws, size_t ws_size,
                              hipStream_t stream)
{
    const float* seq       = (const float*)d_in[0];
    const float* freq      = (const float*)d_in[1];
    const float* presv     = (const float*)d_in[2];
    const float* enrich    = (const float*)d_in[3];
    const float* pw1       = (const float*)d_in[4];
    const float* pb1       = (const float*)d_in[5];
    const float* pw2       = (const float*)d_in[6];
    const float* pb2       = (const float*)d_in[7];
    const float* pw3       = (const float*)d_in[8];
    const float* pb3       = (const float*)d_in[9];
    const float* fw1       = (const float*)d_in[10];
    const float* fb1       = (const float*)d_in[11];
    const float* fw2       = (const float*)d_in[12];
    const float* fb2       = (const float*)d_in[13];
    const float* fw3       = (const float*)d_in[14];
    const float* fb3       = (const float*)d_in[15];
    const int*   perm_idx  = (const int*)d_in[16];
    const int*   round_mask= (const int*)d_in[17];
    float* out = (float*)d_out;

    char* w = (char*)d_ws;
    u16* sb  = (u16*)w;  w += (size_t)BATCH * 512 * 2;   // 16 MB
    u16* Z   = (u16*)w;  w += (size_t)BATCH * 1024 * 2;  // 32 MB
    u16* W1T = (u16*)w;  w += (size_t)1024 * 512 * 2;
    u16* W2T = (u16*)w;  w += (size_t)768 * 512 * 2;
    float* bias1 = (float*)w; w += 1024 * 4;
    float* bias2 = (float*)w; w += 768 * 4;
    float* part  = (float*)w;

    // prep
    {
        const int total = BATCH * 512 + 1024 * 512 + 768 * 512 + 1024 + 768;
        int grid = (total + 255) / 256;
        prep_kernel<<<grid, 256, 0, stream>>>(seq, pw1, pw2, fw1, fw2, pb1, pb2, fb1, fb2,
                                              sb, W1T, W2T, bias1, bias2);
    }

    // Z = seq @ [pw1[:512] | fw1[:512]] + bias1   (M=16384, N=1024, K=512)
    gemm_bf16<<<dim3(BATCH / 128, 1024 / 128), 256, 0, stream>>>(
        sb, 512, W1T, bias1, Z, BATCH, 1024, 512);

    // fused 3-step decode: 512 blocks x 1024 threads, 2 blocks/CU
    decode3<<<NPART, 1024, 0, stream>>>(
        Z, pw1 + (size_t)512 * 512, fw1 + (size_t)512 * 512,
        W2T, bias2, pw3, pb3, fw3, fb3,
        freq, presv, enrich, round_mask, perm_idx, part, out);

    finalize_kernel<<<1, 256, 0, stream>>>(part, out);
}

// Round 12
// 407.628 us; speedup vs baseline: 1.1180x; 1.0664x over previous
//
#include <hip/hip_runtime.h>
#include <hip/hip_bf16.h>
#include <math.h>

#define BATCH 16384

typedef unsigned short u16;
typedef short bf16x8 __attribute__((ext_vector_type(8)));
typedef float f32x4 __attribute__((ext_vector_type(4)));
typedef u16 u16x8 __attribute__((ext_vector_type(8)));
typedef u16 u16x2 __attribute__((ext_vector_type(2)));

__constant__ int PERMS_C[6][3] = {{0,1,2},{0,2,1},{1,0,2},{1,2,0},{2,0,1},{2,1,0}};

__device__ inline float bf2f(u16 u) {
    unsigned int x = ((unsigned int)u) << 16;
    float f; __builtin_memcpy(&f, &x, 4); return f;
}
__device__ inline u16 f2bf(float f) {
    __hip_bfloat16 h = __float2bfloat16(f);
    u16 u; __builtin_memcpy(&u, &h, 2); return u;
}
// tanh-approx gelu: x * sigmoid(1.5957691x + 0.0713548x^3). |err| ~3e-4.
__device__ __forceinline__ float gelu_fast(float x) {
    float t = x * (1.59576912f + x * x * 0.07135481f);
    return x / (1.0f + __expf(-t));
}

// async global->LDS, 16B per lane, wave-uniform LDS base + lane*16
__device__ inline void gload_lds16(const u16* g, u16* l) {
    __builtin_amdgcn_global_load_lds(
        (const __attribute__((address_space(1))) unsigned int*)g,
        (__attribute__((address_space(3))) unsigned int*)l,
        16, 0, 0);
}

// ---------------------------------------------------------------------------
// prep: seq->bf16, transposed bf16 weight blocks, biases, and W1X: the
// packed state->H1 weight matrix [1024 cols][32 k] bf16 (block-diagonal):
//   col<512 : k 0-5 = pw1 rows 512..517, k 6-8 = pw1 rows 518..520, else 0
//   col>=512: k 16-27 = fw1 rows 512..523, k 28-30 = fw1 rows 524..526, else 0
// ---------------------------------------------------------------------------
__global__ __launch_bounds__(256) void prep_kernel(
    const float* __restrict__ seq,
    const float* __restrict__ pw1, const float* __restrict__ pw2,
    const float* __restrict__ fw1, const float* __restrict__ fw2,
    const float* __restrict__ pb1, const float* __restrict__ pb2,
    const float* __restrict__ fb1, const float* __restrict__ fb2,
    u16* __restrict__ sb, u16* __restrict__ W1T, u16* __restrict__ W2T,
    float* __restrict__ bias1, float* __restrict__ bias2,
    u16* __restrict__ W1X)
{
    const int N0 = BATCH * 512;
    const int N1 = 1024 * 512;
    const int N2 = 768 * 512;
    const int N3 = 1024;
    const int N4 = 768;
    const int N5 = 1024 * 32;
    int i = blockIdx.x * 256 + threadIdx.x;
    if (i < N0) { sb[i] = f2bf(seq[i]); return; }
    i -= N0;
    if (i < N1) {
        int n = i >> 9, k = i & 511;
        float v = (n < 512) ? pw1[(size_t)k * 512 + n] : fw1[(size_t)k * 512 + (n - 512)];
        W1T[i] = f2bf(v); return;
    }
    i -= N1;
    if (i < N2) {
        int n = i >> 9, k = i & 511;
        float v = (n < 256) ? pw2[(size_t)k * 256 + n] : fw2[(size_t)k * 512 + (n - 256)];
        W2T[i] = f2bf(v); return;
    }
    i -= N2;
    if (i < N3) { bias1[i] = (i < 512) ? pb1[i] : fb1[i - 512]; return; }
    i -= N3;
    if (i < N4) { bias2[i] = (i < 256) ? pb2[i] : fb2[i - 256]; return; }
    i -= N4;
    if (i < N5) {
        int col = i >> 5, k = i & 31;
        float v = 0.f;
        if (col < 512) {
            if (k < 6)       v = pw1[(size_t)(512 + k) * 512 + col];
            else if (k < 9)  v = pw1[(size_t)(518 + (k - 6)) * 512 + col];
        } else {
            int c2 = col - 512;
            if (k >= 16 && k < 28)      v = fw1[(size_t)(512 + (k - 16)) * 512 + c2];
            else if (k >= 28 && k < 31) v = fw1[(size_t)(524 + (k - 28)) * 512 + c2];
        }
        W1X[i] = f2bf(v); return;
    }
}

// ---------------------------------------------------------------------------
// bf16 MFMA GEMM (unchanged, Z only)
// ---------------------------------------------------------------------------
__global__ __launch_bounds__(256) void gemm_bf16(
    const u16* __restrict__ A, int lda,
    const u16* __restrict__ Bt, const float* __restrict__ bias,
    u16* __restrict__ C, int M, int N, int K)
{
    __shared__ __align__(16) u16 As[128 * 64];
    __shared__ __align__(16) u16 Bs[128 * 64];

    const int bm = blockIdx.x * 128;
    const int bn = blockIdx.y * 128;
    const int tid = threadIdx.x;
    const int wv = tid >> 6;
    const int lane = tid & 63;
    const int wr = wv >> 1;
    const int wc = wv & 1;
    const int lrow = lane >> 3;
    const int lcol = (lane & 7) << 3;

    f32x4 acc[4][4];
#pragma unroll
    for (int i = 0; i < 4; ++i)
#pragma unroll
        for (int j = 0; j < 4; ++j) acc[i][j] = (f32x4){0.f, 0.f, 0.f, 0.f};

    for (int k0 = 0; k0 < K; k0 += 64) {
#pragma unroll
        for (int q = 0; q < 4; ++q) {
            const int c = wv * 4 + q;
            const int row = c * 8 + lrow;
            gload_lds16(&A[(size_t)(bm + row) * lda + k0 + lcol], &As[c * 512]);
            gload_lds16(&Bt[(size_t)(bn + row) * K + k0 + lcol], &Bs[c * 512]);
        }
        __syncthreads();

#pragma unroll
        for (int ks = 0; ks < 64; ks += 32) {
            int kk = ks + (lane >> 4) * 8;
            bf16x8 af[4], bfr[4];
#pragma unroll
            for (int i = 0; i < 4; ++i)
                af[i] = *reinterpret_cast<const bf16x8*>(&As[(wr * 64 + i * 16 + (lane & 15)) * 64 + kk]);
#pragma unroll
            for (int j = 0; j < 4; ++j)
                bfr[j] = *reinterpret_cast<const bf16x8*>(&Bs[(wc * 64 + j * 16 + (lane & 15)) * 64 + kk]);
#pragma unroll
            for (int i = 0; i < 4; ++i)
#pragma unroll
                for (int j = 0; j < 4; ++j)
                    acc[i][j] = __builtin_amdgcn_mfma_f32_16x16x32_bf16(af[i], bfr[j], acc[i][j], 0, 0, 0);
        }
        __syncthreads();
    }

    const int r4 = (lane >> 4) * 4;
    const int cn = lane & 15;
#pragma unroll
    for (int i = 0; i < 4; ++i) {
#pragma unroll
        for (int j = 0; j < 4; ++j) {
            int gcol = bn + wc * 64 + j * 16 + cn;
            float bsv = bias[gcol];
#pragma unroll
            for (int r = 0; r < 4; ++r) {
                int grow = bm + wr * 64 + i * 16 + r4 + r;
                C[(size_t)grow * N + gcol] = f2bf(acc[i][j][r] + bsv);
            }
        }
    }
}

// ---------------------------------------------------------------------------
// decode3 v6: H1 state-delta via MFMA (D = Sx @ W1X) -- NO per-thread weight
// arrays anywhere, so nothing to spill at the 64-VGPR target. 32 rows/block,
// 1024 threads, 512 blocks. Z staged to LDS once. Sx (32x32 bf16 state+onehot
// matrix) lives in LDS, updated by the tail each step.
// ---------------------------------------------------------------------------
__global__ __launch_bounds__(1024) void decode3(
    const u16* __restrict__ Z, const u16* __restrict__ W1X,
    const u16* __restrict__ W2T, const float* __restrict__ bias2,
    const float* __restrict__ pw3, const float* __restrict__ pb3,
    const float* __restrict__ fw3, const float* __restrict__ fb3,
    const float* __restrict__ freq, const float* __restrict__ presv,
    const float* __restrict__ enrich, const int* __restrict__ round_mask,
    const int* __restrict__ perm_idx,
    float* __restrict__ part, float* __restrict__ out)
{
    __shared__ __align__(16) u16 Zs[32 * 1024];    // 64 KB linear
    __shared__ __align__(16) u16 H1s[32 * 1024];   // 64 KB XOR-swizzled
    __shared__ __align__(16) u16 Sx[32 * 32];      // 2 KB  [row][k]
    __shared__ float redh[16][32][3];              // 6 KB
    __shared__ int pidx_s[32];
    __shared__ int rid_s[32];

    const int tid = threadIdx.x;
    const int wv  = tid >> 6;   // 0..15
    const int l   = tid & 63;
    const int row0 = blockIdx.x * 32;
    char* h1base = reinterpret_cast<char*>(H1s);

    // ---- stage Z slice (64 KB contiguous) ----
    {
        const u16* zsrc = Z + (size_t)row0 * 1024;
#pragma unroll
        for (int q = 0; q < 4; ++q) {
            const int c = wv * 4 + q;
            gload_lds16(zsrc + c * 512 + l * 8, &Zs[c * 512]);
        }
    }
    // ---- zero Sx, load perm ----
    if (tid < 512) reinterpret_cast<unsigned int*>(Sx)[tid] = 0u;
    if (tid < 32) {
        int pp = perm_idx[row0 + tid];
        pidx_s[tid] = pp;
        rid_s[tid] = PERMS_C[pp][0];
    }
    __syncthreads();   // drains Z staging too
    if (tid < 32) {
        int r0 = rid_s[tid];
#pragma unroll
        for (int j = 0; j < 3; ++j) {
            Sx[tid * 32 + 6 + j]  = (j == r0) ? (u16)0x3F80 : (u16)0;
            Sx[tid * 32 + 28 + j] = (j == r0) ? (u16)0x3F80 : (u16)0;
        }
    }
    __syncthreads();

    // H2-phase wave geometry: wave wv covers W2 cols [wv*48, wv*48+48)
    const int colbase = wv * 48;
    const bool needP = (colbase < 256);
    const bool needF = (colbase + 32) >= 256;

    float lf_acc = 0.f, bce_acc = 0.f, le_acc = 0.f, mm_acc = 0.f;

#pragma unroll 1
    for (int step = 0; step < 3; ++step) {
        asm volatile("" ::: "memory");
        // ---------------- H1 phase: D = Sx @ W1X; H1 = gelu(Z + D) ---------
        {
            f32x4 hacc[2][4];
#pragma unroll
            for (int rf = 0; rf < 2; ++rf)
#pragma unroll
                for (int cf = 0; cf < 4; ++cf) hacc[rf][cf] = (f32x4){0.f, 0.f, 0.f, 0.f};
            const int ar = l & 15;
            const int ksh = (l >> 4) * 8;
            bf16x8 sa0 = *reinterpret_cast<const bf16x8*>(&Sx[ar * 32 + ksh]);
            bf16x8 sa1 = *reinterpret_cast<const bf16x8*>(&Sx[(16 + ar) * 32 + ksh]);
#pragma unroll
            for (int cf = 0; cf < 4; ++cf) {
                int col = wv * 64 + cf * 16 + ar;
                bf16x8 bw = *reinterpret_cast<const bf16x8*>(&W1X[col * 32 + ksh]);
                hacc[0][cf] = __builtin_amdgcn_mfma_f32_16x16x32_bf16(sa0, bw, hacc[0][cf], 0, 0, 0);
                hacc[1][cf] = __builtin_amdgcn_mfma_f32_16x16x32_bf16(sa1, bw, hacc[1][cf], 0, 0, 0);
            }
#pragma unroll
            for (int rf = 0; rf < 2; ++rf)
#pragma unroll
            for (int cf = 0; cf < 4; ++cf)
#pragma unroll
            for (int g = 0; g < 4; ++g) {
                int row = rf * 16 + (l >> 4) * 4 + g;
                int col = wv * 64 + cf * 16 + ar;
                float h = gelu_fast(bf2f(Zs[row * 1024 + col]) + hacc[rf][cf][g]);
                int byte = (row * 2048 + col * 2) ^ ((row & 7) << 4);
                *reinterpret_cast<u16*>(h1base + byte) = f2bf(h);
            }
        }
        __syncthreads();

        // ---------------- H2 GEMM (P-pass then F-pass) ---------------------
        f32x4 acc[2][3];
#pragma unroll
        for (int rf = 0; rf < 2; ++rf)
#pragma unroll
            for (int cf = 0; cf < 3; ++cf) acc[rf][cf] = (f32x4){0.f, 0.f, 0.f, 0.f};

        const int ar = l & 15;
        const int ks = (l >> 4) * 8;
        const int swz = (ar & 7) << 4;

        if (needP) {
            for (int kf = 0; kf < 16; ++kf) {
                const int kb = (kf * 32 + ks) * 2;
                bf16x8 af0 = *reinterpret_cast<const bf16x8*>(h1base + ((ar * 2048 + kb) ^ swz));
                bf16x8 af1 = *reinterpret_cast<const bf16x8*>(h1base + (((16 + ar) * 2048 + kb) ^ swz));
#pragma unroll
                for (int cf = 0; cf < 3; ++cf) {
                    if (colbase + cf * 16 < 256) {
                        int col = colbase + cf * 16 + ar;
                        bf16x8 bfr = *reinterpret_cast<const bf16x8*>(&W2T[(size_t)col * 512 + kf * 32 + ks]);
                        acc[0][cf] = __builtin_amdgcn_mfma_f32_16x16x32_bf16(af0, bfr, acc[0][cf], 0, 0, 0);
                        acc[1][cf] = __builtin_amdgcn_mfma_f32_16x16x32_bf16(af1, bfr, acc[1][cf], 0, 0, 0);
                    }
                }
            }
        }
        if (needF) {
            for (int kf = 0; kf < 16; ++kf) {
                const int kb = 1024 + (kf * 32 + ks) * 2;
                bf16x8 af0 = *reinterpret_cast<const bf16x8*>(h1base + ((ar * 2048 + kb) ^ swz));
                bf16x8 af1 = *reinterpret_cast<const bf16x8*>(h1base + (((16 + ar) * 2048 + kb) ^ swz));
#pragma unroll
                for (int cf = 0; cf < 3; ++cf) {
                    if (colbase + cf * 16 >= 256) {
                        int col = colbase + cf * 16 + ar;
                        bf16x8 bfr = *reinterpret_cast<const bf16x8*>(&W2T[(size_t)col * 512 + kf * 32 + ks]);
                        acc[0][cf] = __builtin_amdgcn_mfma_f32_16x16x32_bf16(af0, bfr, acc[0][cf], 0, 0, 0);
                        acc[1][cf] = __builtin_amdgcn_mfma_f32_16x16x32_bf16(af1, bfr, acc[1][cf], 0, 0, 0);
                    }
                }
            }
        }

        // ---------------- head readout ----------------
#pragma unroll
        for (int rf = 0; rf < 2; ++rf) {
            float hsp[4] = {0.f, 0.f, 0.f, 0.f};
            float hsf[4] = {0.f, 0.f, 0.f, 0.f};
            float hse[4] = {0.f, 0.f, 0.f, 0.f};
#pragma unroll
            for (int cf = 0; cf < 3; ++cf) {
                const int colc = colbase + cf * 16;
                const int col = colc + ar;
                const float b2 = bias2[col];
                if (colc < 256) {
                    const float w3 = pw3[col];
#pragma unroll
                    for (int g = 0; g < 4; ++g) {
                        float h = gelu_fast(acc[rf][cf][g] + b2);
                        hsp[g] += h * w3;
                    }
                } else {
                    const float wf = fw3[(col - 256) * 2];
                    const float we = fw3[(col - 256) * 2 + 1];
#pragma unroll
                    for (int g = 0; g < 4; ++g) {
                        float h = gelu_fast(acc[rf][cf][g] + b2);
                        hsf[g] += h * wf;
                        hse[g] += h * we;
                    }
                }
            }
#pragma unroll
            for (int g = 0; g < 4; ++g) {
                float a = hsp[g], b = hsf[g], c = hse[g];
#pragma unroll
                for (int m = 1; m < 16; m <<= 1) {
                    a += __shfl_xor(a, m);
                    b += __shfl_xor(b, m);
                    c += __shfl_xor(c, m);
                }
                if ((l & 15) == 0) {
                    int row = rf * 16 + (l >> 4) * 4 + g;
                    redh[wv][row][0] = a;
                    redh[wv][row][1] = b;
                    redh[wv][row][2] = c;
                }
            }
        }
        __syncthreads();

        // ---------------- tail (wave 0, lanes 0..31) ----------------
        if (wv == 0 && l < 32) {
            const int row = l;
            const int b = row0 + row;
            float sp = 0.f, sf = 0.f, se = 0.f;
#pragma unroll
            for (int w2 = 0; w2 < 16; ++w2) {
                sp += redh[w2][row][0];
                sf += redh[w2][row][1];
                se += redh[w2][row][2];
            }
            float logit = sp + pb3[0];
            float pf    = sf + fb3[0];
            float pe    = se + fb3[1];
            int ridx = rid_s[row];
            float gt_f = freq[b * 3 + ridx];
            float gt_p = presv[b * 3 + ridx];
            float gt_e = enrich[b * 3 + ridx];
            float m = (float)round_mask[b * 3 + ridx];
            lf_acc  += (pf - gt_f) * (pf - gt_f) * m;
            bce_acc += (fmaxf(logit, 0.f) - logit * gt_p + log1pf(expf(-fabsf(logit)))) * m;
            le_acc  += (pe - gt_e) * (pe - gt_e) * m;
            mm_acc  += m;
            bool msk = m > 0.5f;
            float act_f = msk ? fminf(fmaxf(pf, -10.f), 10.f) : gt_f;
            float act_p = msk ? 1.f / (1.f + expf(-logit)) : gt_p;
            float act_e = msk ? fminf(fmaxf(pe, -100.f), 100.f) : gt_e;
            // state updates into Sx (bf16)
            Sx[row * 32 + ridx * 2 + 0] = f2bf(act_p);
            Sx[row * 32 + ridx * 2 + 1] = (u16)0x3F80;
            Sx[row * 32 + 16 + ridx * 4 + 0] = f2bf(act_f);
            Sx[row * 32 + 16 + ridx * 4 + 1] = f2bf(act_p);
            Sx[row * 32 + 16 + ridx * 4 + 2] = f2bf(act_e);
            Sx[row * 32 + 16 + ridx * 4 + 3] = (u16)0x3F80;
            out[3 + b * 3 + ridx] = act_f;
            out[3 + 3 * BATCH + b * 3 + ridx] = act_p;
            out[3 + 6 * BATCH + b * 3 + ridx] = act_e;
            if (step < 2) {
                int rn = PERMS_C[pidx_s[row]][step + 1];
                rid_s[row] = rn;
#pragma unroll
                for (int j = 0; j < 3; ++j) {
                    Sx[row * 32 + 6 + j]  = (j == rn) ? (u16)0x3F80 : (u16)0;
                    Sx[row * 32 + 28 + j] = (j == rn) ? (u16)0x3F80 : (u16)0;
                }
            }
        }
        __syncthreads();
    }

    // ---- per-block loss partials ----
    if (wv == 0) {
        for (int off = 32; off > 0; off >>= 1) {
            lf_acc  += __shfl_down(lf_acc, off);
            bce_acc += __shfl_down(bce_acc, off);
            le_acc  += __shfl_down(le_acc, off);
            mm_acc  += __shfl_down(mm_acc, off);
        }
        if (l == 0) {
            float4 v; v.x = lf_acc; v.y = bce_acc; v.z = le_acc; v.w = mm_acc;
            *reinterpret_cast<float4*>(&part[blockIdx.x * 4]) = v;
        }
    }
}

#define NPART (BATCH / 32)

__global__ __launch_bounds__(256) void finalize_kernel(
    const float* __restrict__ part, float* __restrict__ out)
{
    __shared__ float red[4][4];
    float a0 = 0.f, a1 = 0.f, a2 = 0.f, a3 = 0.f;
    for (int j = threadIdx.x; j < NPART; j += 256) {
        float4 v = *reinterpret_cast<const float4*>(&part[j * 4]);
        a0 += v.x; a1 += v.y; a2 += v.z; a3 += v.w;
    }
    for (int off = 32; off > 0; off >>= 1) {
        a0 += __shfl_down(a0, off);
        a1 += __shfl_down(a1, off);
        a2 += __shfl_down(a2, off);
        a3 += __shfl_down(a3, off);
    }
    const int wid = threadIdx.x >> 6, lane = threadIdx.x & 63;
    if (lane == 0) { red[wid][0] = a0; red[wid][1] = a1; red[wid][2] = a2; red[wid][3] = a3; }
    __syncthreads();
    if (threadIdx.x == 0) {
        float s0 = 0.f, s1 = 0.f, s2 = 0.f, s3 = 0.f;
#pragma unroll
        for (int w2 = 0; w2 < 4; ++w2) {
            s0 += red[w2][0]; s1 += red[w2][1]; s2 += red[w2][2]; s3 += red[w2][3];
        }
        float nm = s3 + 1e-8f;
        out[0] = s0 / nm;
        out[1] = s1 / nm;
        out[2] = s2 / nm;
    }
}

// ---------------------------------------------------------------------------
extern "C" void kernel_launch(void* const* d_in, const int* in_sizes, int n_in,
                              void* d_out, int out_size, void* d_ws, size_t ws_size,
                              hipStream_t stream)
{
    const float* seq       = (const float*)d_in[0];
    const float* freq      = (const float*)d_in[1];
    const float* presv     = (const float*)d_in[2];
    const float* enrich    = (const float*)d_in[3];
    const float* pw1       = (const float*)d_in[4];
    const float* pb1       = (const float*)d_in[5];
    const float* pw2       = (const float*)d_in[6];
    const float* pb2       = (const float*)d_in[7];
    const float* pw3       = (const float*)d_in[8];
    const float* pb3       = (const float*)d_in[9];
    const float* fw1       = (const float*)d_in[10];
    const float* fb1       = (const float*)d_in[11];
    const float* fw2       = (const float*)d_in[12];
    const float* fb2       = (const float*)d_in[13];
    const float* fw3       = (const float*)d_in[14];
    const float* fb3       = (const float*)d_in[15];
    const int*   perm_idx  = (const int*)d_in[16];
    const int*   round_mask= (const int*)d_in[17];
    float* out = (float*)d_out;

    char* w = (char*)d_ws;
    u16* sb  = (u16*)w;  w += (size_t)BATCH * 512 * 2;   // 16 MB
    u16* Z   = (u16*)w;  w += (size_t)BATCH * 1024 * 2;  // 32 MB
    u16* W1T = (u16*)w;  w += (size_t)1024 * 512 * 2;
    u16* W2T = (u16*)w;  w += (size_t)768 * 512 * 2;
    float* bias1 = (float*)w; w += 1024 * 4;
    float* bias2 = (float*)w; w += 768 * 4;
    u16* W1X = (u16*)w;  w += (size_t)1024 * 32 * 2;     // 64 KB
    float* part  = (float*)w;

    // prep
    {
        const int total = BATCH * 512 + 1024 * 512 + 768 * 512 + 1024 + 768 + 1024 * 32;
        int grid = (total + 255) / 256;
        prep_kernel<<<grid, 256, 0, stream>>>(seq, pw1, pw2, fw1, fw2, pb1, pb2, fb1, fb2,
                                              sb, W1T, W2T, bias1, bias2, W1X);
    }

    // Z = seq @ [pw1[:512] | fw1[:512]] + bias1   (M=16384, N=1024, K=512)
    gemm_bf16<<<dim3(BATCH / 128, 1024 / 128), 256, 0, stream>>>(
        sb, 512, W1T, bias1, Z, BATCH, 1024, 512);

    // fused 3-step decode
    decode3<<<NPART, 1024, 0, stream>>>(
        Z, W1X, W2T, bias2, pw3, pb3, fw3, fb3,
        freq, presv, enrich, round_mask, perm_idx, part, out);

    finalize_kernel<<<1, 256, 0, stream>>>(part, out);
}